// Round 5
// baseline (194.951 us; speedup 1.0000x reference)
//
#include <hip/hip_runtime.h>
#include <cstdint>
#include <cstddef>

#define NTOK 16384
#define DDIM 1024
#define NE 64
#define CAP 80
#define BM 64
#define BK 32
#define DISP_SZ 83886080LL   // 4*4096*64*80
#define GATE_BLOCKS 256
#define FILL_BLOCKS 3840
#define TOTAL_F4 41943040u   // 2*DISP_SZ/4

typedef float f32x4 __attribute__((ext_vector_type(4)));

// ---------------------------------------------------------------------------
// Kernel 1 (fused): blocks [0,256) do gating GEMM + softmax + top-2 + ballot
// histograms + partial reductions; blocks [256, 4096) stream-zero the 671 MB
// output with PLAIN cached float4 stores (rocclr's fill hits 6.7 TB/s with
// plain stores; round-3's nontemporal variant ran ~4.5-5 TB/s).
// ---------------------------------------------------------------------------
__global__ __launch_bounds__(256)
void gate_fused(const float* __restrict__ x, const float* __restrict__ w,
                int* __restrict__ rec_i1, int* __restrict__ rec_i2,
                float* __restrict__ rec_g1, float* __restrict__ rec_g2,
                unsigned long long* __restrict__ masks1,
                unsigned long long* __restrict__ masks2,
                int* __restrict__ hist1, int* __restrict__ hist2,
                float* __restrict__ proxy_part,   // [256][64]
                float* __restrict__ zsum_part,    // [256]
                float* __restrict__ out)          // dispatch base (fill target)
{
    if (blockIdx.x >= GATE_BLOCKS) {
        // ---------------- fill role: stream zeros, plain stores ----------------
        const unsigned nth = FILL_BLOCKS * 256;
        unsigned tid = (blockIdx.x - GATE_BLOCKS) * 256 + threadIdx.x;
        f32x4* o = reinterpret_cast<f32x4*>(out);
        const f32x4 z = {0.f, 0.f, 0.f, 0.f};
        for (unsigned i = tid; i < TOTAL_F4; i += nth)
            o[i] = z;
        return;
    }

    // ---------------- gate role (math identical to round-3 passing kernel) --
    __shared__ float a_t[BM][40];
    __shared__ float b_t[BK][68];
    __shared__ float c_t[BM][65];
    __shared__ float sdeninv[BM];
    __shared__ float sprox[4][NE];

    const int t = threadIdx.x;
    const int m0 = blockIdx.x * BM;

    const int ty = t >> 4, tx = t & 15;
    const int ar = t >> 3, ac = (t & 7) << 2;
    const int br = t >> 4, bc = (t & 15) << 2;

    float acc[4][4];
#pragma unroll
    for (int i = 0; i < 4; ++i)
#pragma unroll
        for (int j = 0; j < 4; ++j) acc[i][j] = 0.f;

    for (int k0 = 0; k0 < DDIM; k0 += BK) {
#pragma unroll
        for (int p = 0; p < 2; ++p) {
            int row = ar + 32 * p;
            *reinterpret_cast<float4*>(&a_t[row][ac]) =
                *reinterpret_cast<const float4*>(&x[(size_t)(m0 + row) * DDIM + k0 + ac]);
        }
#pragma unroll
        for (int p = 0; p < 2; ++p) {
            int row = br + 16 * p;
            *reinterpret_cast<float4*>(&b_t[row][bc]) =
                *reinterpret_cast<const float4*>(&w[(size_t)(k0 + row) * NE + bc]);
        }
        __syncthreads();
#pragma unroll
        for (int k = 0; k < BK; ++k) {
            float av[4], bv[4];
#pragma unroll
            for (int i = 0; i < 4; ++i) av[i] = a_t[ty + 16 * i][k];
#pragma unroll
            for (int j = 0; j < 4; ++j) bv[j] = b_t[k][tx + 16 * j];
#pragma unroll
            for (int i = 0; i < 4; ++i)
#pragma unroll
                for (int j = 0; j < 4; ++j)
                    acc[i][j] = fmaf(av[i], bv[j], acc[i][j]);
        }
        __syncthreads();
    }

#pragma unroll
    for (int i = 0; i < 4; ++i)
#pragma unroll
        for (int j = 0; j < 4; ++j)
            c_t[ty + 16 * i][tx + 16 * j] = acc[i][j];
    __syncthreads();

    if (t < BM) {
        float mx = -INFINITY;
        for (int e = 0; e < NE; ++e) mx = fmaxf(mx, c_t[t][e]);
        float S = 0.f;
        for (int e = 0; e < NE; ++e) {
            float p = expf(c_t[t][e] - mx);
            c_t[t][e] = p;
            S += p;
        }
        float g1 = -1.f, g2 = -1.f; int i1 = 0, i2 = 0;
        for (int e = 0; e < NE; ++e) {
            float g = c_t[t][e] / S;
            if (g > g1)      { g2 = g1; i2 = i1; g1 = g; i1 = e; }
            else if (g > g2) { g2 = g;  i2 = e; }
        }
        float denom = g1 + g2 + 1e-9f;
        int n = m0 + t;
        rec_i1[n] = i1; rec_i2[n] = i2;
        rec_g1[n] = g1 / denom;
        rec_g2[n] = g2 / denom;
        sdeninv[t] = 1.f / S;
        float lse = mx + logf(S);

        unsigned long long mym1 = 0ull, mym2 = 0ull;
        int h1 = 0, h2 = 0;
        for (int e = 0; e < NE; ++e) {
            unsigned long long b1 = __ballot(i1 == e);
            unsigned long long b2 = __ballot(i2 == e);
            if (t == e) { h1 = __popcll(b1); h2 = __popcll(b2); }
            if (i1 == e) mym1 = b1;
            if (i2 == e) mym2 = b2;
        }
        hist1[blockIdx.x * 64 + t] = h1;
        hist2[blockIdx.x * 64 + t] = h2;
        masks1[n] = mym1;
        masks2[n] = mym2;

        float l = lse;
#pragma unroll
        for (int off = 32; off > 0; off >>= 1) l += __shfl_down(l, off);
        if (t == 0) zsum_part[blockIdx.x] = l;
    }
    __syncthreads();

    {
        int e = t & 63, grp = t >> 6;
        float s = 0.f;
        for (int tok = grp * 16; tok < grp * 16 + 16; ++tok)
            s += c_t[tok][e] * sdeninv[tok];
        sprox[grp][e] = s;
    }
    __syncthreads();
    if (t < NE) {
        float s = sprox[0][t] + sprox[1][t] + sprox[2][t] + sprox[3][t];
        proxy_part[blockIdx.x * 64 + t] = s;   // plain store, no atomics
    }
}

// ---------------------------------------------------------------------------
// Kernel 2 (merged post-pass), 65 blocks x 256 threads:
//  blocks [0,64): each block redundantly computes capacity bases for its own
//                 4 chunks (prefix over <=63 chunks, L2-hit loads), then
//                 scatters <=2 nonzeros per token.
//  block 64:      both scalar losses (full hist1/proxy/zsum reductions).
// ---------------------------------------------------------------------------
__global__ __launch_bounds__(256)
void gate_post(const int* __restrict__ hist1, const int* __restrict__ hist2,
               const float* __restrict__ proxy_part,
               const float* __restrict__ zsum_part,
               const int* __restrict__ rec_i1, const int* __restrict__ rec_i2,
               const float* __restrict__ rec_g1, const float* __restrict__ rec_g2,
               const unsigned long long* __restrict__ masks1,
               const unsigned long long* __restrict__ masks2,
               float* __restrict__ out)
{
    const int t = threadIdx.x;
    const int bid = blockIdx.x;

    if (bid == 64) {
        __shared__ float red[256];
        __shared__ float zred[256];
        const int b = t >> 6, e = t & 63;
        int cnt = 0; float ps = 0.f;
        for (int cb = 0; cb < 64; ++cb) {
            int idx = (b * 64 + cb) * 64 + e;
            cnt += hist1[idx];
            ps  += proxy_part[idx];
        }
        red[t]  = (ps * (1.f / 4096.f)) * ((float)cnt * (1.f / 4096.f));
        zred[t] = zsum_part[t];
        __syncthreads();
        for (int s = 128; s > 0; s >>= 1) {
            if (t < s) { red[t] += red[t + s]; zred[t] += zred[t + s]; }
            __syncthreads();
        }
        if (t == 0) {
            out[2 * DISP_SZ]     = red[0] * 16.f;
            out[2 * DISP_SZ + 1] = zred[0] * 0.25f;
        }
        return;
    }

    // ---- scatter blocks: per-block redundant base computation ----
    __shared__ int sb1[4][64];
    __shared__ int sb2[4][64];
    {
        const int cl = t >> 6, e = t & 63;
        const int cg = bid * 4 + cl;       // global chunk index [0,256)
        const int c0 = cg & ~63;           // first chunk of this batch
        int b1 = 0, b2 = 0;
        for (int c = c0; c < cg; ++c) {
            b1 += hist1[c * 64 + e];
            b2 += hist2[c * 64 + e];
        }
        sb1[cl][e] = b1;
        sb2[cl][e] = b2;
    }
    __syncthreads();

    const int n = bid * 256 + t;
    const int j = n & 63;
    const int cl = t >> 6;
    const unsigned long long below = (j == 0) ? 0ull : ((1ull << j) - 1ull);
    float* dispatch = out;
    float* combine  = out + DISP_SZ;

    {
        int i1 = rec_i1[n];
        int pos = sb1[cl][i1] + __popcll(masks1[n] & below);
        float g = rec_g1[n];
        if (pos < CAP && g != 0.f) {
            size_t o = ((size_t)n * NE + i1) * CAP + pos;
            combine[o]  = g;
            dispatch[o] = 1.f;
        }
    }
    {
        int i2 = rec_i2[n];
        int pos = sb2[cl][i2] + __popcll(masks2[n] & below);
        float g = rec_g2[n];
        if (pos < CAP && g != 0.f) {
            size_t o = ((size_t)n * NE + i2) * CAP + pos;
            combine[o]  = g;
            dispatch[o] = 1.f;
        }
    }
}

// ---------------------------------------------------------------------------
extern "C" void kernel_launch(void* const* d_in, const int* in_sizes, int n_in,
                              void* d_out, int out_size, void* d_ws, size_t ws_size,
                              hipStream_t stream)
{
    (void)in_sizes; (void)n_in; (void)ws_size; (void)out_size;
    const float* x = (const float*)d_in[0];   // [4,4096,1024]
    const float* w = (const float*)d_in[1];   // [1024,64]
    float* out = (float*)d_out;
    char*  ws  = (char*)d_ws;

    int*   rec_i1 = (int*)(ws + 0);
    int*   rec_i2 = (int*)(ws + 65536);
    float* rec_g1 = (float*)(ws + 131072);
    float* rec_g2 = (float*)(ws + 196608);
    unsigned long long* masks1 = (unsigned long long*)(ws + 262144);
    unsigned long long* masks2 = (unsigned long long*)(ws + 393216);
    int*   hist1  = (int*)(ws + 524288);
    int*   hist2  = (int*)(ws + 589824);
    float* proxy_part = (float*)(ws + 786432);   // [786432, 851968)
    float* zsum_part  = (float*)(ws + 851968);   // 256 f32

    gate_fused<<<dim3(GATE_BLOCKS + FILL_BLOCKS), dim3(256), 0, stream>>>(
        x, w, rec_i1, rec_i2, rec_g1, rec_g2,
        masks1, masks2, hist1, hist2, proxy_part, zsum_part, out);

    gate_post<<<dim3(65), dim3(256), 0, stream>>>(
        hist1, hist2, proxy_part, zsum_part,
        rec_i1, rec_i2, rec_g1, rec_g2, masks1, masks2, out);
}

// Round 6
// 132.831 us; speedup vs baseline: 1.4677x; 1.4677x over previous
//
#include <hip/hip_runtime.h>
#include <cstdint>
#include <cstddef>

#define NTOK 16384
#define DDIM 1024
#define NE 64
#define CAP 80
#define BM 64
#define BK 32
#define DISP_SZ 83886080LL   // 4*4096*64*80
#define GATE_BLOCKS 256
#define FILL_BLOCKS 3840
#define TOTAL_F4 41943040u   // 2*DISP_SZ/4
#define GATE_FILL_SHARE 7680u                 // f32x4 per gate block (~75% of equal share)
#define GATE_FILL_BASE  39976960u             // TOTAL_F4 - 256*7680
#define FILL_STRIDE     983040u               // 3840*256

typedef float f32x4 __attribute__((ext_vector_type(4)));

// ---------------------------------------------------------------------------
// Kernel 1 (fused): blocks [0,256) do gating GEMM + softmax + top-2 + ballot
// histograms + partial reductions, THEN fill a weighted contiguous slice;
// blocks [256,4096) grid-stride fill the first 39976960 f32x4.
// NONTEMPORAL stores (A/B verified: NT 158 vs plain 195 µs).
// ---------------------------------------------------------------------------
__global__ __launch_bounds__(256)
void gate_fused(const float* __restrict__ x, const float* __restrict__ w,
                int* __restrict__ rec_i1, int* __restrict__ rec_i2,
                float* __restrict__ rec_g1, float* __restrict__ rec_g2,
                unsigned long long* __restrict__ masks1,
                unsigned long long* __restrict__ masks2,
                int* __restrict__ hist1, int* __restrict__ hist2,
                float* __restrict__ proxy_part,   // [256][64]
                float* __restrict__ zsum_part,    // [256]
                float* __restrict__ out)          // dispatch base (fill target)
{
    const int t = threadIdx.x;

    if (blockIdx.x >= GATE_BLOCKS) {
        // ------------- fill-only role: grid-stride over leading region -------
        unsigned tid = (blockIdx.x - GATE_BLOCKS) * 256 + t;
        f32x4* o = reinterpret_cast<f32x4*>(out);
        const f32x4 z = {0.f, 0.f, 0.f, 0.f};
        for (unsigned i = tid; i < GATE_FILL_BASE; i += FILL_STRIDE)
            __builtin_nontemporal_store(z, &o[i]);
        return;
    }

    // ---------------- gate role (math identical to round-3 passing kernel) --
    __shared__ float a_t[BM][40];
    __shared__ float b_t[BK][68];
    __shared__ float c_t[BM][65];
    __shared__ float sdeninv[BM];
    __shared__ float sprox[4][NE];

    const int m0 = blockIdx.x * BM;

    const int ty = t >> 4, tx = t & 15;
    const int ar = t >> 3, ac = (t & 7) << 2;
    const int br = t >> 4, bc = (t & 15) << 2;

    float acc[4][4];
#pragma unroll
    for (int i = 0; i < 4; ++i)
#pragma unroll
        for (int j = 0; j < 4; ++j) acc[i][j] = 0.f;

    for (int k0 = 0; k0 < DDIM; k0 += BK) {
#pragma unroll
        for (int p = 0; p < 2; ++p) {
            int row = ar + 32 * p;
            *reinterpret_cast<float4*>(&a_t[row][ac]) =
                *reinterpret_cast<const float4*>(&x[(size_t)(m0 + row) * DDIM + k0 + ac]);
        }
#pragma unroll
        for (int p = 0; p < 2; ++p) {
            int row = br + 16 * p;
            *reinterpret_cast<float4*>(&b_t[row][bc]) =
                *reinterpret_cast<const float4*>(&w[(size_t)(k0 + row) * NE + bc]);
        }
        __syncthreads();
#pragma unroll
        for (int k = 0; k < BK; ++k) {
            float av[4], bv[4];
#pragma unroll
            for (int i = 0; i < 4; ++i) av[i] = a_t[ty + 16 * i][k];
#pragma unroll
            for (int j = 0; j < 4; ++j) bv[j] = b_t[k][tx + 16 * j];
#pragma unroll
            for (int i = 0; i < 4; ++i)
#pragma unroll
                for (int j = 0; j < 4; ++j)
                    acc[i][j] = fmaf(av[i], bv[j], acc[i][j]);
        }
        __syncthreads();
    }

#pragma unroll
    for (int i = 0; i < 4; ++i)
#pragma unroll
        for (int j = 0; j < 4; ++j)
            c_t[ty + 16 * i][tx + 16 * j] = acc[i][j];
    __syncthreads();

    if (t < BM) {
        float mx = -INFINITY;
        for (int e = 0; e < NE; ++e) mx = fmaxf(mx, c_t[t][e]);
        float S = 0.f;
        for (int e = 0; e < NE; ++e) {
            float p = expf(c_t[t][e] - mx);
            c_t[t][e] = p;
            S += p;
        }
        float g1 = -1.f, g2 = -1.f; int i1 = 0, i2 = 0;
        for (int e = 0; e < NE; ++e) {
            float g = c_t[t][e] / S;
            if (g > g1)      { g2 = g1; i2 = i1; g1 = g; i1 = e; }
            else if (g > g2) { g2 = g;  i2 = e; }
        }
        float denom = g1 + g2 + 1e-9f;
        int n = m0 + t;
        rec_i1[n] = i1; rec_i2[n] = i2;
        rec_g1[n] = g1 / denom;
        rec_g2[n] = g2 / denom;
        sdeninv[t] = 1.f / S;
        float lse = mx + logf(S);

        unsigned long long mym1 = 0ull, mym2 = 0ull;
        int h1 = 0, h2 = 0;
        for (int e = 0; e < NE; ++e) {
            unsigned long long b1 = __ballot(i1 == e);
            unsigned long long b2 = __ballot(i2 == e);
            if (t == e) { h1 = __popcll(b1); h2 = __popcll(b2); }
            if (i1 == e) mym1 = b1;
            if (i2 == e) mym2 = b2;
        }
        hist1[blockIdx.x * 64 + t] = h1;
        hist2[blockIdx.x * 64 + t] = h2;
        masks1[n] = mym1;
        masks2[n] = mym2;

        float l = lse;
#pragma unroll
        for (int off = 32; off > 0; off >>= 1) l += __shfl_down(l, off);
        if (t == 0) zsum_part[blockIdx.x] = l;
    }
    __syncthreads();

    {
        int e = t & 63, grp = t >> 6;
        float s = 0.f;
        for (int tok = grp * 16; tok < grp * 16 + 16; ++tok)
            s += c_t[tok][e] * sdeninv[tok];
        sprox[grp][e] = s;
    }
    __syncthreads();
    if (t < NE) {
        float s = sprox[0][t] + sprox[1][t] + sprox[2][t] + sprox[3][t];
        proxy_part[blockIdx.x * 64 + t] = s;   // plain store, no atomics
    }

    // ---- gate block's weighted fill slice (contiguous, trailing region) ----
    {
        unsigned base = GATE_FILL_BASE + (unsigned)blockIdx.x * GATE_FILL_SHARE;
        f32x4* o = reinterpret_cast<f32x4*>(out);
        const f32x4 z = {0.f, 0.f, 0.f, 0.f};
        for (unsigned k = t; k < GATE_FILL_SHARE; k += 256)
            __builtin_nontemporal_store(z, &o[base + k]);
    }
}

// ---------------------------------------------------------------------------
// Kernel 2 (merged post-pass, validated in round 5), 65 blocks x 256 threads:
//  blocks [0,64): redundant per-block capacity bases + scatter;
//  block 64:      both scalar losses.
// ---------------------------------------------------------------------------
__global__ __launch_bounds__(256)
void gate_post(const int* __restrict__ hist1, const int* __restrict__ hist2,
               const float* __restrict__ proxy_part,
               const float* __restrict__ zsum_part,
               const int* __restrict__ rec_i1, const int* __restrict__ rec_i2,
               const float* __restrict__ rec_g1, const float* __restrict__ rec_g2,
               const unsigned long long* __restrict__ masks1,
               const unsigned long long* __restrict__ masks2,
               float* __restrict__ out)
{
    const int t = threadIdx.x;
    const int bid = blockIdx.x;

    if (bid == 64) {
        __shared__ float red[256];
        __shared__ float zred[256];
        const int b = t >> 6, e = t & 63;
        int cnt = 0; float ps = 0.f;
        for (int cb = 0; cb < 64; ++cb) {
            int idx = (b * 64 + cb) * 64 + e;
            cnt += hist1[idx];
            ps  += proxy_part[idx];
        }
        red[t]  = (ps * (1.f / 4096.f)) * ((float)cnt * (1.f / 4096.f));
        zred[t] = zsum_part[t];
        __syncthreads();
        for (int s = 128; s > 0; s >>= 1) {
            if (t < s) { red[t] += red[t + s]; zred[t] += zred[t + s]; }
            __syncthreads();
        }
        if (t == 0) {
            out[2 * DISP_SZ]     = red[0] * 16.f;
            out[2 * DISP_SZ + 1] = zred[0] * 0.25f;
        }
        return;
    }

    __shared__ int sb1[4][64];
    __shared__ int sb2[4][64];
    {
        const int cl = t >> 6, e = t & 63;
        const int cg = bid * 4 + cl;       // global chunk index [0,256)
        const int c0 = cg & ~63;           // first chunk of this batch
        int b1 = 0, b2 = 0;
        for (int c = c0; c < cg; ++c) {
            b1 += hist1[c * 64 + e];
            b2 += hist2[c * 64 + e];
        }
        sb1[cl][e] = b1;
        sb2[cl][e] = b2;
    }
    __syncthreads();

    const int n = bid * 256 + t;
    const int j = n & 63;
    const int cl = t >> 6;
    const unsigned long long below = (j == 0) ? 0ull : ((1ull << j) - 1ull);
    float* dispatch = out;
    float* combine  = out + DISP_SZ;

    {
        int i1 = rec_i1[n];
        int pos = sb1[cl][i1] + __popcll(masks1[n] & below);
        float g = rec_g1[n];
        if (pos < CAP && g != 0.f) {
            size_t o = ((size_t)n * NE + i1) * CAP + pos;
            combine[o]  = g;
            dispatch[o] = 1.f;
        }
    }
    {
        int i2 = rec_i2[n];
        int pos = sb2[cl][i2] + __popcll(masks2[n] & below);
        float g = rec_g2[n];
        if (pos < CAP && g != 0.f) {
            size_t o = ((size_t)n * NE + i2) * CAP + pos;
            combine[o]  = g;
            dispatch[o] = 1.f;
        }
    }
}

// ---------------------------------------------------------------------------
extern "C" void kernel_launch(void* const* d_in, const int* in_sizes, int n_in,
                              void* d_out, int out_size, void* d_ws, size_t ws_size,
                              hipStream_t stream)
{
    (void)in_sizes; (void)n_in; (void)ws_size; (void)out_size;
    const float* x = (const float*)d_in[0];   // [4,4096,1024]
    const float* w = (const float*)d_in[1];   // [1024,64]
    float* out = (float*)d_out;
    char*  ws  = (char*)d_ws;

    int*   rec_i1 = (int*)(ws + 0);
    int*   rec_i2 = (int*)(ws + 65536);
    float* rec_g1 = (float*)(ws + 131072);
    float* rec_g2 = (float*)(ws + 196608);
    unsigned long long* masks1 = (unsigned long long*)(ws + 262144);
    unsigned long long* masks2 = (unsigned long long*)(ws + 393216);
    int*   hist1  = (int*)(ws + 524288);
    int*   hist2  = (int*)(ws + 589824);
    float* proxy_part = (float*)(ws + 786432);   // [786432, 851968)
    float* zsum_part  = (float*)(ws + 851968);   // 256 f32

    gate_fused<<<dim3(GATE_BLOCKS + FILL_BLOCKS), dim3(256), 0, stream>>>(
        x, w, rec_i1, rec_i2, rec_g1, rec_g2,
        masks1, masks2, hist1, hist2, proxy_part, zsum_part, out);

    gate_post<<<dim3(65), dim3(256), 0, stream>>>(
        hist1, hist2, proxy_part, zsum_part,
        rec_i1, rec_i2, rec_g1, rec_g2, masks1, masks2, out);
}